// Round 6
// baseline (179.581 us; speedup 1.0000x reference)
//
#include <hip/hip_runtime.h>
#include <cmath>

#define BB   512
#define NSV  128
#define NTRK 512
#define KK   8
#define HH   16
#define TPB  256
#define PSTR 20            // padded proj stride in LDS
#define KSTR 17            // padded key-buffer stride (odd -> 2-way max)

__device__ __forceinline__ float elu_f(float x) {
    return x > 0.0f ? x : expm1f(x);
}
__device__ __forceinline__ unsigned umin_u(unsigned a, unsigned b) { return a < b ? a : b; }
__device__ __forceinline__ unsigned med3u(unsigned a, unsigned b, unsigned c) {
    unsigned d;
    asm("v_med3_u32 %0, %1, %2, %3" : "=v"(d) : "v"(a), "v"(b), "v"(c));
    return d;
}

// ---------------- kernel 1: per-SV precompute into workspace ----------------
__global__ __launch_bounds__(NSV) void precompute(
    const float* __restrict__ x_sv,
    const float* __restrict__ W1s, const float* __restrict__ b1s,
    const float* __restrict__ W2s, const float* __restrict__ b2s,
    const float* __restrict__ We,  const float* __restrict__ be,
    const float* __restrict__ Wo,  const float* __restrict__ bo,
    float* __restrict__ svf_g, float* __restrict__ proj_g,
    float* __restrict__ hsq_g, float* __restrict__ uc_g,
    float* __restrict__ pool_g, unsigned* __restrict__ cnt_g)
{
    const int b = blockIdx.x, s = threadIdx.x;

    if (s == 0) { pool_g[b] = 0.0f; cnt_g[b] = 0u; }   // re-init every call

    const float* xp = x_sv + (size_t)(b * NSV + s) * 2;
    float x0 = xp[0], x1 = xp[1];
    float hb[HH];
    #pragma unroll
    for (int h = 0; h < HH; ++h)
        hb[h] = elu_f(x0 * W1s[h] + x1 * W1s[HH + h] + b1s[h]);

    float o[HH];
    float sq = 0.0f;
    #pragma unroll
    for (int h2 = 0; h2 < HH; ++h2) {
        float a = b2s[h2];
        #pragma unroll
        for (int h = 0; h < HH; ++h) a += hb[h] * W2s[h * HH + h2];
        o[h2] = a;
        sq += a * a;
    }

    float* sdst = svf_g + (size_t)(b * NSV + s) * HH;
    #pragma unroll
    for (int h4 = 0; h4 < 4; ++h4)
        *(float4*)&sdst[h4 * 4] = make_float4(o[h4*4], o[h4*4+1], o[h4*4+2], o[h4*4+3]);
    hsq_g[b * NSV + s] = 0.5f * sq;

    float* pdst = proj_g + (size_t)(b * NSV + s) * HH;
    #pragma unroll
    for (int h4 = 0; h4 < 4; ++h4) {
        float p[4];
        #pragma unroll
        for (int q = 0; q < 4; ++q) {
            int h = h4 * 4 + q;
            float a = 0.0f;
            #pragma unroll
            for (int j = 0; j < HH; ++j) a += o[j] * We[(HH + j) * HH + h];
            p[q] = a;
        }
        *(float4*)&pdst[h4 * 4] = make_float4(p[0], p[1], p[2], p[3]);
    }

    // u[j] = sum_h Wdiff[j][h]*Wo[h];  c0 = bo + be.Wo
    if (b == 0) {
        if (s < HH) {
            float a = 0.0f;
            #pragma unroll
            for (int h = 0; h < HH; ++h)
                a += (We[s * HH + h] - We[(HH + s) * HH + h]) * Wo[h];
            uc_g[s] = a;
        } else if (s == HH) {
            float a = bo[0];
            #pragma unroll
            for (int h = 0; h < HH; ++h) a += be[h] * Wo[h];
            uc_g[HH] = a;
        }
    }
}

// ------- kernel 2: 2048 blocks x 256 thr; 2 waves-halves per track-set -------
__global__ __launch_bounds__(TPB, 8) void fused_main(
    const float* __restrict__ x_trk,
    const float* __restrict__ W1t, const float* __restrict__ b1t,
    const float* __restrict__ W2t, const float* __restrict__ b2t,
    const float* __restrict__ Wo,
    const float* __restrict__ svf_g, const float* __restrict__ proj_g,
    const float* __restrict__ hsq_g, const float* __restrict__ uc_g,
    float* __restrict__ pool_g, unsigned* __restrict__ cnt_g,
    float* __restrict__ out)
{
    __shared__ float    proj[NSV][PSTR];
    __shared__ unsigned kbuf[NSV][KSTR];   // [track_local][half*8+q]
    __shared__ float    sred[TPB / 64];

    const int blk = blockIdx.x;
    const int b   = blk >> 2, qtr = blk & 3;
    const int tid = threadIdx.x;
    const int tl  = tid & 127;                                   // local track
    const int trk = qtr * 128 + tl;
    const int sh  = __builtin_amdgcn_readfirstlane(tid >> 7);    // wave-uniform 0/1

    // issue proj-staging loads now; store to LDS after the scan
    float4 stv[2]; int ss[2], sq4[2];
    #pragma unroll
    for (int r = 0; r < 2; ++r) {
        int e = tid + r * TPB;          // 0..511 of 512 float4 chunks
        ss[r] = e >> 2; sq4[r] = e & 3;
        stv[r] = *(const float4*)&proj_g[(size_t)(b * NSV + ss[r]) * HH + sq4[r] * 4];
    }

    // track MLP (uniform weights -> scalar loads); both halves compute same track
    float tf[HH], ntf[HH], htsq;
    {
        const float* xp = x_trk + (size_t)(b * NTRK + trk) * 8;
        float x[8];
        *(float4*)&x[0] = *(const float4*)&xp[0];
        *(float4*)&x[4] = *(const float4*)&xp[4];
        float hb[HH];
        #pragma unroll
        for (int h = 0; h < HH; ++h) {
            float a = b1t[h];
            #pragma unroll
            for (int i = 0; i < 8; ++i) a += x[i] * W1t[i * HH + h];
            hb[h] = elu_f(a);
        }
        float sq = 0.0f;
        #pragma unroll
        for (int h2 = 0; h2 < HH; ++h2) {
            float a = b2t[h2];
            #pragma unroll
            for (int h = 0; h < HH; ++h) a += hb[h] * W2t[h * HH + h2];
            tf[h2] = a;
            ntf[h2] = -a;
            sq += a * a;
        }
        htsq = 0.5f * sq;
    }

    unsigned k[KK];
    #pragma unroll
    for (int q = 0; q < KK; ++q) k[q] = 0xFFFFFFFFu;

    // ---- scan this half's 64 SV rows (uniform base -> s_load), depth-2 pipe ----
    const int sbase = sh * 64;
    const float* __restrict__ svb = svf_g + (size_t)(b * NSV + sbase) * HH;
    const float* __restrict__ hsb = hsq_g + (size_t)b * NSV + sbase;

    float pa[HH], pb[HH], ha, hbv;

    #define LOADROW(buf, hv, idx)                                \
        do {                                                     \
            const float* _sp = svb + (idx) * HH;                 \
            _Pragma("unroll")                                    \
            for (int _j = 0; _j < HH; ++_j) buf[_j] = _sp[_j];   \
            hv = hsb[idx];                                       \
        } while (0)

    #define BODY(buf, hv, idx)                                        \
        do {                                                          \
            float a0 = fmaf(ntf[0], buf[0], htsq);                    \
            float a1 = fmaf(ntf[1], buf[1], hv);                      \
            float a2 = ntf[2] * buf[2];                               \
            float a3 = ntf[3] * buf[3];                               \
            _Pragma("unroll")                                         \
            for (int _j = 4; _j < HH; _j += 4) {                      \
                a0 = fmaf(ntf[_j],     buf[_j],     a0);              \
                a1 = fmaf(ntf[_j + 1], buf[_j + 1], a1);              \
                a2 = fmaf(ntf[_j + 2], buf[_j + 2], a2);              \
                a3 = fmaf(ntf[_j + 3], buf[_j + 3], a3);              \
            }                                                         \
            float e = fmaxf((a0 + a1) + (a2 + a3), 0.0f);             \
            unsigned v = (__float_as_uint(e) & 0xFFFFFF80u)           \
                         | (unsigned)(sbase + (idx));                 \
            unsigned nk0 = umin_u(v, k[0]);                           \
            unsigned nk1 = med3u(v, k[0], k[1]);                      \
            unsigned nk2 = med3u(v, k[1], k[2]);                      \
            unsigned nk3 = med3u(v, k[2], k[3]);                      \
            unsigned nk4 = med3u(v, k[3], k[4]);                      \
            unsigned nk5 = med3u(v, k[4], k[5]);                      \
            unsigned nk6 = med3u(v, k[5], k[6]);                      \
            unsigned nk7 = med3u(v, k[6], k[7]);                      \
            k[0] = nk0; k[1] = nk1; k[2] = nk2; k[3] = nk3;           \
            k[4] = nk4; k[5] = nk5; k[6] = nk6; k[7] = nk7;           \
        } while (0)

    LOADROW(pa, ha, 0);
    LOADROW(pb, hbv, 1);
    for (int s = 0; s < 64 - 2; s += 2) {
        BODY(pa, ha, s);
        LOADROW(pa, ha, s + 2);
        BODY(pb, hbv, s + 1);
        LOADROW(pb, hbv, s + 3);
    }
    BODY(pa, ha, 62);
    BODY(pb, hbv, 63);

    #undef LOADROW
    #undef BODY

    // publish own sorted list; store staged proj; one barrier
    #pragma unroll
    for (int q = 0; q < KK; ++q) kbuf[tl][sh * 8 + q] = k[q];
    #pragma unroll
    for (int r = 0; r < 2; ++r)
        *(float4*)&proj[ss[r]][sq4[r] * 4] = stv[r];
    __syncthreads();

    // bitonic half-clean merge with partner half: 8 smallest of the union
    unsigned m[KK];
    {
        const unsigned* pk = &kbuf[tl][(sh ^ 1) * 8];
        #pragma unroll
        for (int i = 0; i < KK; ++i) m[i] = umin_u(k[i], pk[7 - i]);
    }

    // ---- epilogue: acc = c0 + tf.u + sum_h max_k(proj)[h]*Wo[h] ----
    float local;
    {
        float acc = uc_g[HH];
        #pragma unroll
        for (int j = 0; j < HH; ++j) acc = fmaf(tf[j], uc_g[j], acc);

        float mx[HH];
        #pragma unroll
        for (int h = 0; h < HH; ++h) mx[h] = -INFINITY;
        #pragma unroll
        for (int q = 0; q < KK; ++q) {
            const float* pr = &proj[m[q] & 127u][0];
            #pragma unroll
            for (int h4 = 0; h4 < 4; ++h4) {
                float4 p = *(const float4*)&pr[h4 * 4];
                mx[h4 * 4 + 0] = fmaxf(mx[h4 * 4 + 0], p.x);
                mx[h4 * 4 + 1] = fmaxf(mx[h4 * 4 + 1], p.y);
                mx[h4 * 4 + 2] = fmaxf(mx[h4 * 4 + 2], p.z);
                mx[h4 * 4 + 3] = fmaxf(mx[h4 * 4 + 3], p.w);
            }
        }
        #pragma unroll
        for (int h = 0; h < HH; ++h) acc = fmaf(mx[h], Wo[h], acc);
        local = 1.0f / (1.0f + expf(-acc));   // each track computed twice (both halves)
    }

    // ---- block partial sum (256 values = 128 tracks x2), then cross-block ----
    #pragma unroll
    for (int off = 32; off > 0; off >>= 1)
        local += __shfl_down(local, off, 64);
    if ((tid & 63) == 0) sred[tid >> 6] = local;
    __syncthreads();
    if (tid == 0) {
        float part = sred[0] + sred[1] + sred[2] + sred[3];
        atomicAdd(&pool_g[b], part);
        __threadfence();
        unsigned old = atomicAdd(&cnt_g[b], 1u);
        if (old == 3u) {   // last of 4 blocks for this batch
            float tot = atomicAdd(&pool_g[b], 0.0f);   // coherent read-back
            out[b]      = tot * (1.0f / (2 * NTRK));   // each track counted twice
            out[BB + b] = (float)b;
        }
    }
}

extern "C" void kernel_launch(void* const* d_in, const int* in_sizes, int n_in,
                              void* d_out, int out_size, void* d_ws, size_t ws_size,
                              hipStream_t stream) {
    const float* x_sv  = (const float*)d_in[0];
    const float* x_trk = (const float*)d_in[1];
    const float* W1s = (const float*)d_in[4];
    const float* b1s = (const float*)d_in[5];
    const float* W2s = (const float*)d_in[6];
    const float* b2s = (const float*)d_in[7];
    const float* W1t = (const float*)d_in[8];
    const float* b1t = (const float*)d_in[9];
    const float* W2t = (const float*)d_in[10];
    const float* b2t = (const float*)d_in[11];
    const float* We  = (const float*)d_in[12];
    const float* be  = (const float*)d_in[13];
    const float* Wo  = (const float*)d_in[14];
    const float* bo  = (const float*)d_in[15];
    float* out = (float*)d_out;

    float*    svf_g  = (float*)d_ws;                    // 4 MB
    float*    proj_g = svf_g  + (size_t)BB * NSV * HH;  // 4 MB
    float*    hsq_g  = proj_g + (size_t)BB * NSV * HH;  // 256 KB
    float*    uc_g   = hsq_g  + (size_t)BB * NSV;       // 32 floats
    float*    pool_g = uc_g   + 32;                     // 512 floats
    unsigned* cnt_g  = (unsigned*)(pool_g + BB);        // 512 uints

    precompute<<<BB, NSV, 0, stream>>>(x_sv, W1s, b1s, W2s, b2s, We, be, Wo, bo,
                                       svf_g, proj_g, hsq_g, uc_g, pool_g, cnt_g);
    fused_main<<<BB * 4, TPB, 0, stream>>>(x_trk, W1t, b1t, W2t, b2t, Wo,
                                           svf_g, proj_g, hsq_g, uc_g,
                                           pool_g, cnt_g, out);
}

// Round 7
// 168.979 us; speedup vs baseline: 1.0627x; 1.0627x over previous
//
#include <hip/hip_runtime.h>
#include <cmath>

#define BB   512
#define NSV  128
#define NTRK 512
#define KK   8
#define HH   16
#define TPB  512
#define RSTR 20            // svf row stride in floats: [16 feats][hsq][pad x3]
#define PSTR 20            // padded proj stride in LDS

typedef float vf4 __attribute__((ext_vector_type(4)));

__device__ __forceinline__ float elu_f(float x) {
    return x > 0.0f ? x : expm1f(x);
}
__device__ __forceinline__ unsigned umin_u(unsigned a, unsigned b) { return a < b ? a : b; }
__device__ __forceinline__ unsigned med3u(unsigned a, unsigned b, unsigned c) {
    unsigned d;
    asm("v_med3_u32 %0, %1, %2, %3" : "=v"(d) : "v"(a), "v"(b), "v"(c));
    return d;
}

// ---------------- kernel 1: per-SV precompute into workspace ----------------
// svf_g rows of 20 floats: [0..15]=features, [16]=0.5*||sv||^2
__global__ __launch_bounds__(NSV) void precompute(
    const float* __restrict__ x_sv,
    const float* __restrict__ W1s, const float* __restrict__ b1s,
    const float* __restrict__ W2s, const float* __restrict__ b2s,
    const float* __restrict__ We,  const float* __restrict__ be,
    const float* __restrict__ Wo,  const float* __restrict__ bo,
    float* __restrict__ svf_g, float* __restrict__ proj_g,
    float* __restrict__ uc_g)
{
    const int b = blockIdx.x, s = threadIdx.x;

    const float* xp = x_sv + (size_t)(b * NSV + s) * 2;
    float x0 = xp[0], x1 = xp[1];
    float hb[HH];
    #pragma unroll
    for (int h = 0; h < HH; ++h)
        hb[h] = elu_f(x0 * W1s[h] + x1 * W1s[HH + h] + b1s[h]);

    float o[HH];
    float sq = 0.0f;
    #pragma unroll
    for (int h2 = 0; h2 < HH; ++h2) {
        float a = b2s[h2];
        #pragma unroll
        for (int h = 0; h < HH; ++h) a += hb[h] * W2s[h * HH + h2];
        o[h2] = a;
        sq += a * a;
    }

    float* sdst = svf_g + (size_t)(b * NSV + s) * RSTR;
    #pragma unroll
    for (int h4 = 0; h4 < 4; ++h4)
        *(float4*)&sdst[h4 * 4] = make_float4(o[h4*4], o[h4*4+1], o[h4*4+2], o[h4*4+3]);
    sdst[HH] = 0.5f * sq;

    float* pdst = proj_g + (size_t)(b * NSV + s) * HH;
    #pragma unroll
    for (int h4 = 0; h4 < 4; ++h4) {
        float p[4];
        #pragma unroll
        for (int q = 0; q < 4; ++q) {
            int h = h4 * 4 + q;
            float a = 0.0f;
            #pragma unroll
            for (int j = 0; j < HH; ++j) a += o[j] * We[(HH + j) * HH + h];
            p[q] = a;
        }
        *(float4*)&pdst[h4 * 4] = make_float4(p[0], p[1], p[2], p[3]);
    }

    // u[j] = sum_h Wdiff[j][h]*Wo[h];  c0 = bo + be.Wo
    if (b == 0) {
        if (s < HH) {
            float a = 0.0f;
            #pragma unroll
            for (int h = 0; h < HH; ++h)
                a += (We[s * HH + h] - We[(HH + s) * HH + h]) * Wo[h];
            uc_g[s] = a;
        } else if (s == HH) {
            float a = bo[0];
            #pragma unroll
            for (int h = 0; h < HH; ++h) a += be[h] * Wo[h];
            uc_g[HH] = a;
        }
    }
}

// ---------------- kernel 2: track MLP + kNN + edge-max + pool ----------------
__global__ __launch_bounds__(TPB, 4) void fused_main(
    const float* __restrict__ x_trk,
    const float* __restrict__ W1t, const float* __restrict__ b1t,
    const float* __restrict__ W2t, const float* __restrict__ b2t,
    const float* __restrict__ Wo,
    const float* __restrict__ svf_g, const float* __restrict__ proj_g,
    const float* __restrict__ uc_g,
    float* __restrict__ out)
{
    __shared__ float proj[NSV][PSTR];
    __shared__ float sred[TPB / 64];

    const int b = blockIdx.x, tid = threadIdx.x;

    // stage proj -> LDS (coalesced: 512 threads x float4 = 8 KB)
    {
        int s = tid >> 2, q = tid & 3;
        float4 p = *(const float4*)&proj_g[(size_t)(b * NSV + s) * HH + q * 4];
        *(float4*)&proj[s][q * 4] = p;
    }

    // track MLP (uniform weights -> scalar loads)
    float tf[HH], htsq;
    {
        const float* xp = x_trk + (size_t)(b * NTRK + tid) * 8;
        float x[8];
        *(float4*)&x[0] = *(const float4*)&xp[0];
        *(float4*)&x[4] = *(const float4*)&xp[4];
        float hb[HH];
        #pragma unroll
        for (int h = 0; h < HH; ++h) {
            float a = b1t[h];
            #pragma unroll
            for (int i = 0; i < 8; ++i) a += x[i] * W1t[i * HH + h];
            hb[h] = elu_f(a);
        }
        float sq = 0.0f;
        #pragma unroll
        for (int h2 = 0; h2 < HH; ++h2) {
            float a = b2t[h2];
            #pragma unroll
            for (int h = 0; h < HH; ++h) a += hb[h] * W2t[h * HH + h2];
            tf[h2] = a;
            sq += a * a;
        }
        htsq = 0.5f * sq;
    }

    unsigned k[KK];
    #pragma unroll
    for (int q = 0; q < KK; ++q) k[q] = 0xFFFFFFFFu;

    __syncthreads();   // proj staged

    // ---- kNN scan: asm VMEM pipeline, depth 4 rows, vmcnt(15) steady state ----
    // Row = 80 B at uniform (SGPR) address; saddr-form global_load broadcasts
    // one 64B-line fetch per instr; L1-resident for later waves of this block.
    const float* ip = svf_g + (size_t)b * NSV * RSTR;   // SGPR issue pointer
    unsigned vzero = 0;                                  // zero voffset (VGPR)

    vf4 q00, q01, q02, q03; float h0;
    vf4 q10, q11, q12, q13; float h1;
    vf4 q20, q21, q22, q23; float h2;
    vf4 q30, q31, q32, q33; float h3;

    #define ISSUE_ROW(R)                                                   \
        do {                                                               \
            asm volatile(                                                  \
                "global_load_dwordx4 %0, %5, %6 offset:0\n\t"              \
                "global_load_dwordx4 %1, %5, %6 offset:16\n\t"             \
                "global_load_dwordx4 %2, %5, %6 offset:32\n\t"             \
                "global_load_dwordx4 %3, %5, %6 offset:48\n\t"             \
                "global_load_dword %4, %5, %6 offset:64"                   \
                : "=v"(q##R##0), "=v"(q##R##1), "=v"(q##R##2),             \
                  "=v"(q##R##3), "=v"(h##R)                                \
                : "v"(vzero), "s"(ip));                                    \
            ip += RSTR;                                                    \
        } while (0)

    #define WAIT_ROW(R)                                                    \
        asm volatile("s_waitcnt vmcnt(15)"                                 \
                     : "+v"(q##R##0), "+v"(q##R##1), "+v"(q##R##2),        \
                       "+v"(q##R##3), "+v"(h##R))

    #define BODY(a, bq, c, d, hv, idx)                                     \
        do {                                                               \
            float a0 = fmaf(-tf[0], a[0], htsq);                           \
            float a1 = fmaf(-tf[1], a[1], hv);                             \
            float a2 = -tf[2] * a[2];                                      \
            float a3 = -tf[3] * a[3];                                      \
            a0 = fmaf(-tf[4],  bq[0], a0); a1 = fmaf(-tf[5],  bq[1], a1);  \
            a2 = fmaf(-tf[6],  bq[2], a2); a3 = fmaf(-tf[7],  bq[3], a3);  \
            a0 = fmaf(-tf[8],  c[0],  a0); a1 = fmaf(-tf[9],  c[1],  a1);  \
            a2 = fmaf(-tf[10], c[2],  a2); a3 = fmaf(-tf[11], c[3],  a3);  \
            a0 = fmaf(-tf[12], d[0],  a0); a1 = fmaf(-tf[13], d[1],  a1);  \
            a2 = fmaf(-tf[14], d[2],  a2); a3 = fmaf(-tf[15], d[3],  a3);  \
            float e = fmaxf((a0 + a1) + (a2 + a3), 0.0f);                  \
            unsigned v = (__float_as_uint(e) & 0xFFFFFF80u)                \
                         | (unsigned)(idx);                                \
            unsigned nk0 = umin_u(v, k[0]);                                \
            unsigned nk1 = med3u(v, k[0], k[1]);                           \
            unsigned nk2 = med3u(v, k[1], k[2]);                           \
            unsigned nk3 = med3u(v, k[2], k[3]);                           \
            unsigned nk4 = med3u(v, k[3], k[4]);                           \
            unsigned nk5 = med3u(v, k[4], k[5]);                           \
            unsigned nk6 = med3u(v, k[5], k[6]);                           \
            unsigned nk7 = med3u(v, k[6], k[7]);                           \
            k[0] = nk0; k[1] = nk1; k[2] = nk2; k[3] = nk3;                \
            k[4] = nk4; k[5] = nk5; k[6] = nk6; k[7] = nk7;                \
        } while (0)

    ISSUE_ROW(0); ISSUE_ROW(1); ISSUE_ROW(2); ISSUE_ROW(3);
    for (int s = 0; s < NSV; s += 4) {
        // issues run 4 rows past the end (valid ws memory); drained below
        WAIT_ROW(0); BODY(q00, q01, q02, q03, h0, s + 0); ISSUE_ROW(0);
        WAIT_ROW(1); BODY(q10, q11, q12, q13, h1, s + 1); ISSUE_ROW(1);
        WAIT_ROW(2); BODY(q20, q21, q22, q23, h2, s + 2); ISSUE_ROW(2);
        WAIT_ROW(3); BODY(q30, q31, q32, q33, h3, s + 3); ISSUE_ROW(3);
    }
    // drain the over-issued junk loads before their registers can be reused
    asm volatile("s_waitcnt vmcnt(0)"
                 : "+v"(q00), "+v"(q01), "+v"(q02), "+v"(q03), "+v"(h0),
                   "+v"(q10), "+v"(q11), "+v"(q12), "+v"(q13), "+v"(h1),
                   "+v"(q20), "+v"(q21), "+v"(q22), "+v"(q23), "+v"(h2),
                   "+v"(q30), "+v"(q31), "+v"(q32), "+v"(q33), "+v"(h3));

    #undef ISSUE_ROW
    #undef WAIT_ROW
    #undef BODY

    // ---- epilogue: acc = c0 + tf.u + sum_h max_k(proj)[h]*Wo[h] ----
    float local;
    {
        float acc = uc_g[HH];
        #pragma unroll
        for (int j = 0; j < HH; ++j) acc = fmaf(tf[j], uc_g[j], acc);

        float mx[HH];
        #pragma unroll
        for (int h = 0; h < HH; ++h) mx[h] = -INFINITY;
        #pragma unroll
        for (int q = 0; q < KK; ++q) {
            const float* pr = &proj[k[q] & 127u][0];
            #pragma unroll
            for (int h4 = 0; h4 < 4; ++h4) {
                float4 p = *(const float4*)&pr[h4 * 4];
                mx[h4 * 4 + 0] = fmaxf(mx[h4 * 4 + 0], p.x);
                mx[h4 * 4 + 1] = fmaxf(mx[h4 * 4 + 1], p.y);
                mx[h4 * 4 + 2] = fmaxf(mx[h4 * 4 + 2], p.z);
                mx[h4 * 4 + 3] = fmaxf(mx[h4 * 4 + 3], p.w);
            }
        }
        #pragma unroll
        for (int h = 0; h < HH; ++h) acc = fmaf(mx[h], Wo[h], acc);
        local = 1.0f / (1.0f + expf(-acc));
    }

    // ---- block mean-pool ----
    #pragma unroll
    for (int off = 32; off > 0; off >>= 1)
        local += __shfl_down(local, off, 64);
    if ((tid & 63) == 0) sred[tid >> 6] = local;
    __syncthreads();
    if (tid == 0) {
        float tot = 0.0f;
        #pragma unroll
        for (int w = 0; w < TPB / 64; ++w) tot += sred[w];
        out[b]      = tot * (1.0f / NTRK);
        out[BB + b] = (float)b;
    }
}

extern "C" void kernel_launch(void* const* d_in, const int* in_sizes, int n_in,
                              void* d_out, int out_size, void* d_ws, size_t ws_size,
                              hipStream_t stream) {
    const float* x_sv  = (const float*)d_in[0];
    const float* x_trk = (const float*)d_in[1];
    const float* W1s = (const float*)d_in[4];
    const float* b1s = (const float*)d_in[5];
    const float* W2s = (const float*)d_in[6];
    const float* b2s = (const float*)d_in[7];
    const float* W1t = (const float*)d_in[8];
    const float* b1t = (const float*)d_in[9];
    const float* W2t = (const float*)d_in[10];
    const float* b2t = (const float*)d_in[11];
    const float* We  = (const float*)d_in[12];
    const float* be  = (const float*)d_in[13];
    const float* Wo  = (const float*)d_in[14];
    const float* bo  = (const float*)d_in[15];
    float* out = (float*)d_out;

    float* svf_g  = (float*)d_ws;                         // 512*128*20 f ≈ 5.2 MB
    float* proj_g = svf_g  + (size_t)BB * NSV * RSTR;     // 512*128*16 f = 4 MB
    float* uc_g   = proj_g + (size_t)BB * NSV * HH;       // 17 floats

    precompute<<<BB, NSV, 0, stream>>>(x_sv, W1s, b1s, W2s, b2s, We, be, Wo, bo,
                                       svf_g, proj_g, uc_g);
    fused_main<<<BB, TPB, 0, stream>>>(x_trk, W1t, b1t, W2t, b2t, Wo,
                                       svf_g, proj_g, uc_g, out);
}

// Round 8
// 125.293 us; speedup vs baseline: 1.4333x; 1.3487x over previous
//
#include <hip/hip_runtime.h>
#include <cmath>

#define BB   512
#define NSV  128
#define NTRK 512
#define KK   8
#define HH   16
#define TPB  512
#define RSTR 20            // global row stride: [16 feats][0.5*||sv||^2][pad x3]
#define PSTR 20            // padded proj stride in LDS

typedef float vf2 __attribute__((ext_vector_type(2)));

__device__ __forceinline__ float elu_f(float x) {
    return x > 0.0f ? x : expm1f(x);
}
__device__ __forceinline__ unsigned umin_u(unsigned a, unsigned b) { return a < b ? a : b; }
__device__ __forceinline__ unsigned med3u(unsigned a, unsigned b, unsigned c) {
    unsigned d;
    asm("v_med3_u32 %0, %1, %2, %3" : "=v"(d) : "v"(a), "v"(b), "v"(c));
    return d;
}

// Single fused kernel. Block b owns batch b end-to-end:
//  phase A: SV MLP -> row store (global, via svw) + proj -> LDS; u/c0 -> LDS
//  phase B: track MLP (all threads)
//  barrier (drains vmcnt -> rows visible in L2)
//  scan: rows read back through svr (const __restrict alias -> s_load path, L2-hot)
__global__ __launch_bounds__(TPB, 4) void fused_all(
    const float* __restrict__ x_sv, const float* __restrict__ x_trk,
    const float* __restrict__ W1s, const float* __restrict__ b1s,
    const float* __restrict__ W2s, const float* __restrict__ b2s,
    const float* __restrict__ W1t, const float* __restrict__ b1t,
    const float* __restrict__ W2t, const float* __restrict__ b2t,
    const float* __restrict__ We,  const float* __restrict__ be,
    const float* __restrict__ Wo,  const float* __restrict__ bo,
    float* __restrict__ svw,             // ws rows, write alias
    const float* __restrict__ svr,       // ws rows, read alias (scalar loads)
    float* __restrict__ out)
{
    __shared__ float proj[NSV][PSTR];
    __shared__ float ucS[HH + 1];        // u[16], c0
    __shared__ float sred[TPB / 64];

    const int b = blockIdx.x, tid = threadIdx.x;

    // ---- phase A ----
    if (tid < NSV) {
        const float* xp = x_sv + (size_t)(b * NSV + tid) * 2;
        float x0 = xp[0], x1 = xp[1];
        float hb[HH];
        #pragma unroll
        for (int h = 0; h < HH; ++h)
            hb[h] = elu_f(x0 * W1s[h] + x1 * W1s[HH + h] + b1s[h]);
        float o[HH], sq = 0.0f;
        #pragma unroll
        for (int h2 = 0; h2 < HH; ++h2) {
            float a = b2s[h2];
            #pragma unroll
            for (int h = 0; h < HH; ++h) a += hb[h] * W2s[h * HH + h2];
            o[h2] = a;
            sq += a * a;
        }
        float* dst = svw + (size_t)(b * NSV + tid) * RSTR;
        #pragma unroll
        for (int h4 = 0; h4 < 4; ++h4)
            *(float4*)&dst[h4 * 4] = make_float4(o[h4*4], o[h4*4+1], o[h4*4+2], o[h4*4+3]);
        dst[HH] = 0.5f * sq;
        // proj[s][h] = o . We_bot[:,h]  (own row only)
        #pragma unroll
        for (int h = 0; h < HH; ++h) {
            float a = 0.0f;
            #pragma unroll
            for (int j = 0; j < HH; ++j) a += o[j] * We[(HH + j) * HH + h];
            proj[tid][h] = a;
        }
    } else if (tid < NSV + HH) {
        int j = tid - NSV;               // u[j] = sum_h Wdiff[j][h]*Wo[h]
        float a = 0.0f;
        #pragma unroll
        for (int h = 0; h < HH; ++h)
            a += (We[j * HH + h] - We[(HH + j) * HH + h]) * Wo[h];
        ucS[j] = a;
    } else if (tid == NSV + HH) {
        float a = bo[0];
        #pragma unroll
        for (int h = 0; h < HH; ++h) a += be[h] * Wo[h];
        ucS[HH] = a;
    }

    // ---- phase B: track MLP (uniform weights -> scalar loads) ----
    float tf[HH], htsq;
    vf2 ntfp[8];
    {
        const float* xp = x_trk + (size_t)(b * NTRK + tid) * 8;
        float x[8];
        *(float4*)&x[0] = *(const float4*)&xp[0];
        *(float4*)&x[4] = *(const float4*)&xp[4];
        float hb[HH];
        #pragma unroll
        for (int h = 0; h < HH; ++h) {
            float a = b1t[h];
            #pragma unroll
            for (int i = 0; i < 8; ++i) a += x[i] * W1t[i * HH + h];
            hb[h] = elu_f(a);
        }
        float sq = 0.0f;
        #pragma unroll
        for (int h2 = 0; h2 < HH; ++h2) {
            float a = b2t[h2];
            #pragma unroll
            for (int h = 0; h < HH; ++h) a += hb[h] * W2t[h * HH + h2];
            tf[h2] = a;
            sq += a * a;
        }
        htsq = 0.5f * sq;
        #pragma unroll
        for (int j = 0; j < 8; ++j) {
            vf2 t; t.x = -tf[2 * j]; t.y = -tf[2 * j + 1];
            ntfp[j] = t;
        }
    }

    unsigned k[KK];
    #pragma unroll
    for (int q = 0; q < KK; ++q) k[q] = 0xFFFFFFFFu;

    __syncthreads();   // drains row stores (vmcnt0) + proj/uc visible

    // ---- kNN scan: scalar rows (L2-hot), packed-f32 dot, depth-2 pipeline ----
    const float* rp = svr + (size_t)b * NSV * RSTR;

    vf2 pa[8], pb[8]; float ha, hbv;

    #define LOADROW(buf, hv, idx)                                      \
        do {                                                           \
            const float* _r = rp + (size_t)(idx) * RSTR;               \
            _Pragma("unroll")                                          \
            for (int _j = 0; _j < 8; ++_j)                             \
                buf[_j] = *(const vf2*)(_r + 2 * _j);                  \
            hv = _r[HH];                                               \
        } while (0)

    #define BODY(buf, hv, idx)                                         \
        do {                                                           \
            vf2 a0 = ntfp[0] * buf[0];                                 \
            vf2 a1 = ntfp[1] * buf[1];                                 \
            vf2 a2 = ntfp[2] * buf[2];                                 \
            vf2 a3 = ntfp[3] * buf[3];                                 \
            a0 = __builtin_elementwise_fma(ntfp[4], buf[4], a0);       \
            a1 = __builtin_elementwise_fma(ntfp[5], buf[5], a1);       \
            a2 = __builtin_elementwise_fma(ntfp[6], buf[6], a2);       \
            a3 = __builtin_elementwise_fma(ntfp[7], buf[7], a3);       \
            a0 = a0 + a1; a2 = a2 + a3; a0 = a0 + a2;                  \
            float e = fmaxf((htsq + hv) + (a0.x + a0.y), 0.0f);        \
            unsigned v = (__float_as_uint(e) & 0xFFFFFF80u)            \
                         | (unsigned)(idx);                            \
            unsigned nk0 = umin_u(v, k[0]);                            \
            unsigned nk1 = med3u(v, k[0], k[1]);                       \
            unsigned nk2 = med3u(v, k[1], k[2]);                       \
            unsigned nk3 = med3u(v, k[2], k[3]);                       \
            unsigned nk4 = med3u(v, k[3], k[4]);                       \
            unsigned nk5 = med3u(v, k[4], k[5]);                       \
            unsigned nk6 = med3u(v, k[5], k[6]);                       \
            unsigned nk7 = med3u(v, k[6], k[7]);                       \
            k[0] = nk0; k[1] = nk1; k[2] = nk2; k[3] = nk3;            \
            k[4] = nk4; k[5] = nk5; k[6] = nk6; k[7] = nk7;            \
        } while (0)

    LOADROW(pa, ha, 0);
    LOADROW(pb, hbv, 1);
    for (int s = 0; s < NSV - 2; s += 2) {
        BODY(pa, ha, s);
        LOADROW(pa, ha, s + 2);
        BODY(pb, hbv, s + 1);
        LOADROW(pb, hbv, s + 3);
    }
    BODY(pa, ha, NSV - 2);
    BODY(pb, hbv, NSV - 1);

    #undef LOADROW
    #undef BODY

    // ---- epilogue: acc = c0 + tf.u + sum_h max_k(proj)[h]*Wo[h] ----
    float local;
    {
        float acc = ucS[HH];
        #pragma unroll
        for (int j = 0; j < HH; ++j) acc = fmaf(tf[j], ucS[j], acc);

        float mx[HH];
        #pragma unroll
        for (int h = 0; h < HH; ++h) mx[h] = -INFINITY;
        #pragma unroll
        for (int q = 0; q < KK; ++q) {
            const float* pr = &proj[k[q] & 127u][0];
            #pragma unroll
            for (int h4 = 0; h4 < 4; ++h4) {
                float4 p = *(const float4*)&pr[h4 * 4];
                mx[h4 * 4 + 0] = fmaxf(mx[h4 * 4 + 0], p.x);
                mx[h4 * 4 + 1] = fmaxf(mx[h4 * 4 + 1], p.y);
                mx[h4 * 4 + 2] = fmaxf(mx[h4 * 4 + 2], p.z);
                mx[h4 * 4 + 3] = fmaxf(mx[h4 * 4 + 3], p.w);
            }
        }
        #pragma unroll
        for (int h = 0; h < HH; ++h) acc = fmaf(mx[h], Wo[h], acc);
        local = 1.0f / (1.0f + expf(-acc));
    }

    // ---- block mean-pool ----
    #pragma unroll
    for (int off = 32; off > 0; off >>= 1)
        local += __shfl_down(local, off, 64);
    if ((tid & 63) == 0) sred[tid >> 6] = local;
    __syncthreads();
    if (tid == 0) {
        float tot = 0.0f;
        #pragma unroll
        for (int w = 0; w < TPB / 64; ++w) tot += sred[w];
        out[b]      = tot * (1.0f / NTRK);
        out[BB + b] = (float)b;
    }
}

extern "C" void kernel_launch(void* const* d_in, const int* in_sizes, int n_in,
                              void* d_out, int out_size, void* d_ws, size_t ws_size,
                              hipStream_t stream) {
    const float* x_sv  = (const float*)d_in[0];
    const float* x_trk = (const float*)d_in[1];
    const float* W1s = (const float*)d_in[4];
    const float* b1s = (const float*)d_in[5];
    const float* W2s = (const float*)d_in[6];
    const float* b2s = (const float*)d_in[7];
    const float* W1t = (const float*)d_in[8];
    const float* b1t = (const float*)d_in[9];
    const float* W2t = (const float*)d_in[10];
    const float* b2t = (const float*)d_in[11];
    const float* We  = (const float*)d_in[12];
    const float* be  = (const float*)d_in[13];
    const float* Wo  = (const float*)d_in[14];
    const float* bo  = (const float*)d_in[15];
    float* out = (float*)d_out;

    float* rows = (float*)d_ws;      // 512*128*20 floats ≈ 5.2 MB

    fused_all<<<BB, TPB, 0, stream>>>(x_sv, x_trk,
                                      W1s, b1s, W2s, b2s,
                                      W1t, b1t, W2t, b2t,
                                      We, be, Wo, bo,
                                      rows, rows, out);
}